// Round 8
// baseline (39.507 us; speedup 1.0000x reference)
//
#include <hip/hip_runtime.h>

#define NCH     192
#define TOTAL   (16 * 192 * 64 * 64)   // 12,582,912
#define SLICE4  1024                    // float4 per (b,c) slice
#define NB      16
#define BPB     2                       // batch slices per block
#define NBLK    (NCH * NB / BPB)        // 1536 blocks
#define NK      257                     // LUT points, u in [-8,8], h = 1/16
#define WSTRIDE 260                     // floats per wave-private LUT copy

typedef float fx4 __attribute__((ext_vector_type(4)));

// ---------------- fast device math ----------------
__device__ __forceinline__ float fast_tanh(float x) {
    // tanh(x) = 1 - 2/(exp(2x)+1); overflow -> inf -> rcp -> 0 -> 1 (correct limit)
    float e = __expf(2.0f * x);
    return 1.0f - 2.0f * __builtin_amdgcn_rcpf(e + 1.0f);
}
__device__ __forceinline__ float fast_sigmoid(float x) {
    return __builtin_amdgcn_rcpf(1.0f + __expf(-x));
}
__device__ __forceinline__ float fast_softplus(float x) {
    return fmaxf(x, 0.0f) + __logf(1.0f + __expf(-fabsf(x)));
}

struct Net {
    float m0[3], b0[3], tf0[3];
    float m1[9], b1[3], tf1[3];
    float m2[9], b2[3], tf2[3];
    float m3[9], b3[3], tf3[3];
    float m4[3], b4;
};

__device__ __forceinline__ float eval_fast(float u, const Net& p) {
    float v0 = fmaf(p.m0[0], u, p.b0[0]);
    float v1 = fmaf(p.m0[1], u, p.b0[1]);
    float v2 = fmaf(p.m0[2], u, p.b0[2]);
    v0 = fmaf(p.tf0[0], fast_tanh(v0), v0);
    v1 = fmaf(p.tf0[1], fast_tanh(v1), v1);
    v2 = fmaf(p.tf0[2], fast_tanh(v2), v2);

    float w0 = fmaf(p.m1[0], v0, fmaf(p.m1[1], v1, fmaf(p.m1[2], v2, p.b1[0])));
    float w1 = fmaf(p.m1[3], v0, fmaf(p.m1[4], v1, fmaf(p.m1[5], v2, p.b1[1])));
    float w2 = fmaf(p.m1[6], v0, fmaf(p.m1[7], v1, fmaf(p.m1[8], v2, p.b1[2])));
    w0 = fmaf(p.tf1[0], fast_tanh(w0), w0);
    w1 = fmaf(p.tf1[1], fast_tanh(w1), w1);
    w2 = fmaf(p.tf1[2], fast_tanh(w2), w2);

    float y0 = fmaf(p.m2[0], w0, fmaf(p.m2[1], w1, fmaf(p.m2[2], w2, p.b2[0])));
    float y1 = fmaf(p.m2[3], w0, fmaf(p.m2[4], w1, fmaf(p.m2[5], w2, p.b2[1])));
    float y2 = fmaf(p.m2[6], w0, fmaf(p.m2[7], w1, fmaf(p.m2[8], w2, p.b2[2])));
    y0 = fmaf(p.tf2[0], fast_tanh(y0), y0);
    y1 = fmaf(p.tf2[1], fast_tanh(y1), y1);
    y2 = fmaf(p.tf2[2], fast_tanh(y2), y2);

    float z0 = fmaf(p.m3[0], y0, fmaf(p.m3[1], y1, fmaf(p.m3[2], y2, p.b3[0])));
    float z1 = fmaf(p.m3[3], y0, fmaf(p.m3[4], y1, fmaf(p.m3[5], y2, p.b3[1])));
    float z2 = fmaf(p.m3[6], y0, fmaf(p.m3[7], y1, fmaf(p.m3[8], y2, p.b3[2])));
    z0 = fmaf(p.tf3[0], fast_tanh(z0), z0);
    z1 = fmaf(p.tf3[1], fast_tanh(z1), z1);
    z2 = fmaf(p.tf3[2], fast_tanh(z2), z2);

    return fmaf(p.m4[0], z0, fmaf(p.m4[1], z1, fmaf(p.m4[2], z2, p.b4)));
}

__device__ __forceinline__ float lik_fast(float u, const Net& p) {
    float lo = eval_fast(u - 0.5f, p);
    float hi = eval_fast(u + 0.5f, p);
    float l  = fabsf(fast_sigmoid(hi) - fast_sigmoid(lo));
    return fmaxf(l, 1e-9f);
}

__device__ __forceinline__ fx4 lut_nearest(fx4 u, const float* wlut) {
    fx4 r;
#pragma unroll
    for (int s = 0; s < 4; ++s) {
        float tt = fmaf(u[s], 16.0f, 128.5f);     // +0.5 for nearest rounding
        tt = fminf(fmaxf(tt, 0.0f), 256.0f);
        r[s] = wlut[(int)tt];
    }
    return r;
}

// Fused, BARRIER-FREE: each wave builds its own private LUT copy in LDS
// (4 evals/lane, overlapped with in-flight input loads), then streams BPB
// slices with no __syncthreads anywhere (no forced vmcnt(0) drains).
__global__ __launch_bounds__(256) void eb_fused(
        const fx4* __restrict__ x, const fx4* __restrict__ nz,
        const float* __restrict__ m0, const float* __restrict__ b0, const float* __restrict__ f0,
        const float* __restrict__ m1, const float* __restrict__ b1, const float* __restrict__ f1,
        const float* __restrict__ m2, const float* __restrict__ b2, const float* __restrict__ f2,
        const float* __restrict__ m3, const float* __restrict__ b3, const float* __restrict__ f3,
        const float* __restrict__ m4, const float* __restrict__ b4,
        fx4* __restrict__ out, fx4* __restrict__ lik) {
    __shared__ float slut[4 * WSTRIDE];
    int bid  = blockIdx.x;          // 0..NBLK-1
    int c    = bid % NCH;           // block-uniform -> scalar param loads
    int bg   = bid / NCH;
    int t    = threadIdx.x;
    int lane = t & 63;
    float* wlut = slut + (t >> 6) * WSTRIDE;   // wave-private copy

    int base0 = ((bg * BPB) * NCH + c) * SLICE4 + t;
    int base1 = base0 + NCH * SLICE4;

    // 1) slice-0 loads go in flight; latency hides under the LUT build
    fx4 xa0 = x[base0],  xa1 = x[base0 + 256],  xa2 = x[base0 + 512],  xa3 = x[base0 + 768];
    fx4 na0 = nz[base0], na1 = nz[base0 + 256], na2 = nz[base0 + 512], na3 = nz[base0 + 768];

    // 2) channel params (uniform -> scalar loads) + per-wave LUT build
    Net p;
#pragma unroll
    for (int j = 0; j < 3; ++j) {
        p.m0[j]  = fast_softplus(m0[c * 3 + j]);
        p.b0[j]  = b0[c * 3 + j];
        p.tf0[j] = fast_tanh(f0[c * 3 + j]);
        p.b1[j]  = b1[c * 3 + j];
        p.tf1[j] = fast_tanh(f1[c * 3 + j]);
        p.b2[j]  = b2[c * 3 + j];
        p.tf2[j] = fast_tanh(f2[c * 3 + j]);
        p.b3[j]  = b3[c * 3 + j];
        p.tf3[j] = fast_tanh(f3[c * 3 + j]);
        p.m4[j]  = fast_softplus(m4[c * 3 + j]);
    }
#pragma unroll
    for (int j = 0; j < 9; ++j) {
        p.m1[j] = fast_softplus(m1[c * 9 + j]);
        p.m2[j] = fast_softplus(m2[c * 9 + j]);
        p.m3[j] = fast_softplus(m3[c * 9 + j]);
    }
    p.b4 = b4[c];

#pragma unroll
    for (int j = 0; j < 4; ++j) {
        int k = lane + 64 * j;
        wlut[k] = lik_fast(fmaf((float)k, 1.0f / 16.0f, -8.0f), p);
    }
    if (lane == 0) wlut[256] = lik_fast(8.0f, p);
    // no __syncthreads: only this wave reads wlut (lgkmcnt ordering suffices)

    // 3) slice 0: adds + out stores flow as soon as loads land
    fx4 u0 = xa0 + na0, u1 = xa1 + na1, u2 = xa2 + na2, u3 = xa3 + na3;
    __builtin_nontemporal_store(u0, &out[base0]);
    __builtin_nontemporal_store(u1, &out[base0 + 256]);
    __builtin_nontemporal_store(u2, &out[base0 + 512]);
    __builtin_nontemporal_store(u3, &out[base0 + 768]);

    // slice-1 loads fly during slice-0 gathers/stores
    fx4 xb0 = x[base1],  xb1 = x[base1 + 256],  xb2 = x[base1 + 512],  xb3 = x[base1 + 768];
    fx4 nb0 = nz[base1], nb1 = nz[base1 + 256], nb2 = nz[base1 + 512], nb3 = nz[base1 + 768];

    __builtin_nontemporal_store(lut_nearest(u0, wlut), &lik[base0]);
    __builtin_nontemporal_store(lut_nearest(u1, wlut), &lik[base0 + 256]);
    __builtin_nontemporal_store(lut_nearest(u2, wlut), &lik[base0 + 512]);
    __builtin_nontemporal_store(lut_nearest(u3, wlut), &lik[base0 + 768]);

    // 4) slice 1
    fx4 v0 = xb0 + nb0, v1 = xb1 + nb1, v2 = xb2 + nb2, v3 = xb3 + nb3;
    __builtin_nontemporal_store(v0, &out[base1]);
    __builtin_nontemporal_store(v1, &out[base1 + 256]);
    __builtin_nontemporal_store(v2, &out[base1 + 512]);
    __builtin_nontemporal_store(v3, &out[base1 + 768]);
    __builtin_nontemporal_store(lut_nearest(v0, wlut), &lik[base1]);
    __builtin_nontemporal_store(lut_nearest(v1, wlut), &lik[base1 + 256]);
    __builtin_nontemporal_store(lut_nearest(v2, wlut), &lik[base1 + 512]);
    __builtin_nontemporal_store(lut_nearest(v3, wlut), &lik[base1 + 768]);
}

extern "C" void kernel_launch(void* const* d_in, const int* in_sizes, int n_in,
                              void* d_out, int out_size, void* d_ws, size_t ws_size,
                              hipStream_t stream) {
    const fx4*   x  = (const fx4*)d_in[0];
    const fx4*   nz = (const fx4*)d_in[1];
    const float* m0 = (const float*)d_in[2];
    const float* b0 = (const float*)d_in[3];
    const float* f0 = (const float*)d_in[4];
    const float* m1 = (const float*)d_in[5];
    const float* b1 = (const float*)d_in[6];
    const float* f1 = (const float*)d_in[7];
    const float* m2 = (const float*)d_in[8];
    const float* b2 = (const float*)d_in[9];
    const float* f2 = (const float*)d_in[10];
    const float* m3 = (const float*)d_in[11];
    const float* b3 = (const float*)d_in[12];
    const float* f3 = (const float*)d_in[13];
    const float* m4 = (const float*)d_in[14];
    const float* b4 = (const float*)d_in[15];

    fx4* out = (fx4*)d_out;
    fx4* lik = out + TOTAL / 4;

    eb_fused<<<NBLK, 256, 0, stream>>>(x, nz, m0, b0, f0, m1, b1, f1,
                                       m2, b2, f2, m3, b3, f3, m4, b4,
                                       out, lik);
}

// Round 9
// 37.881 us; speedup vs baseline: 1.0429x; 1.0429x over previous
//
#include <hip/hip_runtime.h>

#define NCH     192
#define TOTAL   (16 * 192 * 64 * 64)   // 12,582,912
#define SLICE4  1024                    // float4 per (b,c) slice
#define NBLK    (TOTAL / 4096)          // 3072 blocks, one slice each
#define NK      256                     // LUT points used, u in [-8,8), h = 1/16

typedef float fx4 __attribute__((ext_vector_type(4)));

// ---------------- fast device math ----------------
__device__ __forceinline__ float fast_tanh(float x) {
    // tanh(x) = 1 - 2/(exp(2x)+1); overflow -> inf -> rcp -> 0 -> 1 (correct limit)
    float e = __expf(2.0f * x);
    return 1.0f - 2.0f * __builtin_amdgcn_rcpf(e + 1.0f);
}
__device__ __forceinline__ float fast_sigmoid(float x) {
    return __builtin_amdgcn_rcpf(1.0f + __expf(-x));
}
__device__ __forceinline__ float fast_softplus(float x) {
    return fmaxf(x, 0.0f) + __logf(1.0f + __expf(-fabsf(x)));
}

struct Net {
    float m0[3], b0[3], tf0[3];
    float m1[9], b1[3], tf1[3];
    float m2[9], b2[3], tf2[3];
    float m3[9], b3[3], tf3[3];
    float m4[3], b4;
};

__device__ __forceinline__ float eval_fast(float u, const Net& p) {
    float v0 = fmaf(p.m0[0], u, p.b0[0]);
    float v1 = fmaf(p.m0[1], u, p.b0[1]);
    float v2 = fmaf(p.m0[2], u, p.b0[2]);
    v0 = fmaf(p.tf0[0], fast_tanh(v0), v0);
    v1 = fmaf(p.tf0[1], fast_tanh(v1), v1);
    v2 = fmaf(p.tf0[2], fast_tanh(v2), v2);

    float w0 = fmaf(p.m1[0], v0, fmaf(p.m1[1], v1, fmaf(p.m1[2], v2, p.b1[0])));
    float w1 = fmaf(p.m1[3], v0, fmaf(p.m1[4], v1, fmaf(p.m1[5], v2, p.b1[1])));
    float w2 = fmaf(p.m1[6], v0, fmaf(p.m1[7], v1, fmaf(p.m1[8], v2, p.b1[2])));
    w0 = fmaf(p.tf1[0], fast_tanh(w0), w0);
    w1 = fmaf(p.tf1[1], fast_tanh(w1), w1);
    w2 = fmaf(p.tf1[2], fast_tanh(w2), w2);

    float y0 = fmaf(p.m2[0], w0, fmaf(p.m2[1], w1, fmaf(p.m2[2], w2, p.b2[0])));
    float y1 = fmaf(p.m2[3], w0, fmaf(p.m2[4], w1, fmaf(p.m2[5], w2, p.b2[1])));
    float y2 = fmaf(p.m2[6], w0, fmaf(p.m2[7], w1, fmaf(p.m2[8], w2, p.b2[2])));
    y0 = fmaf(p.tf2[0], fast_tanh(y0), y0);
    y1 = fmaf(p.tf2[1], fast_tanh(y1), y1);
    y2 = fmaf(p.tf2[2], fast_tanh(y2), y2);

    float z0 = fmaf(p.m3[0], y0, fmaf(p.m3[1], y1, fmaf(p.m3[2], y2, p.b3[0])));
    float z1 = fmaf(p.m3[3], y0, fmaf(p.m3[4], y1, fmaf(p.m3[5], y2, p.b3[1])));
    float z2 = fmaf(p.m3[6], y0, fmaf(p.m3[7], y1, fmaf(p.m3[8], y2, p.b3[2])));
    z0 = fmaf(p.tf3[0], fast_tanh(z0), z0);
    z1 = fmaf(p.tf3[1], fast_tanh(z1), z1);
    z2 = fmaf(p.tf3[2], fast_tanh(z2), z2);

    return fmaf(p.m4[0], z0, fmaf(p.m4[1], z1, fmaf(p.m4[2], z2, p.b4)));
}

__device__ __forceinline__ float lik_fast(float u, const Net& p) {
    float lo = eval_fast(u - 0.5f, p);
    float hi = eval_fast(u + 0.5f, p);
    float l  = fabsf(fast_sigmoid(hi) - fast_sigmoid(lo));
    return fmaxf(l, 1e-9f);
}

__device__ __forceinline__ fx4 lut_nearest(fx4 u, const float* slut) {
    fx4 r;
#pragma unroll
    for (int s = 0; s < 4; ++s) {
        float tt = fmaf(u[s], 16.0f, 128.5f);     // +0.5 for nearest rounding
        tt = fminf(fmaxf(tt, 0.0f), 255.0f);      // clamp to last entry, no tail point
        r[s] = slut[(int)tt];
    }
    return r;
}

// Fused single pass (best structure, R6): per-block 256-point LUT build
// (1 eval/thread, hidden under the 8 in-flight input loads), one barrier,
// then barrier-free streaming with NT stores.
__global__ __launch_bounds__(256) void eb_fused(
        const fx4* __restrict__ x, const fx4* __restrict__ nz,
        const float* __restrict__ m0, const float* __restrict__ b0, const float* __restrict__ f0,
        const float* __restrict__ m1, const float* __restrict__ b1, const float* __restrict__ f1,
        const float* __restrict__ m2, const float* __restrict__ b2, const float* __restrict__ f2,
        const float* __restrict__ m3, const float* __restrict__ b3, const float* __restrict__ f3,
        const float* __restrict__ m4, const float* __restrict__ b4,
        fx4* __restrict__ out, fx4* __restrict__ lik) {
    __shared__ float slut[NK];
    int bid = blockIdx.x;           // one (b,c) slice per block
    int c   = bid % NCH;            // block-uniform -> scalar param loads
    int t   = threadIdx.x;

    int base = bid * SLICE4 + t;

    // 1) issue all 8 input loads; they stay in flight during the LUT build
    fx4 xa0 = x[base],  xa1 = x[base + 256],  xa2 = x[base + 512],  xa3 = x[base + 768];
    fx4 na0 = nz[base], na1 = nz[base + 256], na2 = nz[base + 512], na3 = nz[base + 768];

    // 2) channel params (uniform -> scalar loads) + per-block LUT build
    Net p;
#pragma unroll
    for (int j = 0; j < 3; ++j) {
        p.m0[j]  = fast_softplus(m0[c * 3 + j]);
        p.b0[j]  = b0[c * 3 + j];
        p.tf0[j] = fast_tanh(f0[c * 3 + j]);
        p.b1[j]  = b1[c * 3 + j];
        p.tf1[j] = fast_tanh(f1[c * 3 + j]);
        p.b2[j]  = b2[c * 3 + j];
        p.tf2[j] = fast_tanh(f2[c * 3 + j]);
        p.b3[j]  = b3[c * 3 + j];
        p.tf3[j] = fast_tanh(f3[c * 3 + j]);
        p.m4[j]  = fast_softplus(m4[c * 3 + j]);
    }
#pragma unroll
    for (int j = 0; j < 9; ++j) {
        p.m1[j] = fast_softplus(m1[c * 9 + j]);
        p.m2[j] = fast_softplus(m2[c * 9 + j]);
        p.m3[j] = fast_softplus(m3[c * 9 + j]);
    }
    p.b4 = b4[c];

    slut[t] = lik_fast(fmaf((float)t, 1.0f / 16.0f, -8.0f), p);
    __syncthreads();

    // 3) stream: outputs then LUT-gathered likelihoods, all NT stores
    fx4 u0 = xa0 + na0, u1 = xa1 + na1, u2 = xa2 + na2, u3 = xa3 + na3;
    __builtin_nontemporal_store(u0, &out[base]);
    __builtin_nontemporal_store(u1, &out[base + 256]);
    __builtin_nontemporal_store(u2, &out[base + 512]);
    __builtin_nontemporal_store(u3, &out[base + 768]);
    __builtin_nontemporal_store(lut_nearest(u0, slut), &lik[base]);
    __builtin_nontemporal_store(lut_nearest(u1, slut), &lik[base + 256]);
    __builtin_nontemporal_store(lut_nearest(u2, slut), &lik[base + 512]);
    __builtin_nontemporal_store(lut_nearest(u3, slut), &lik[base + 768]);
}

extern "C" void kernel_launch(void* const* d_in, const int* in_sizes, int n_in,
                              void* d_out, int out_size, void* d_ws, size_t ws_size,
                              hipStream_t stream) {
    const fx4*   x  = (const fx4*)d_in[0];
    const fx4*   nz = (const fx4*)d_in[1];
    const float* m0 = (const float*)d_in[2];
    const float* b0 = (const float*)d_in[3];
    const float* f0 = (const float*)d_in[4];
    const float* m1 = (const float*)d_in[5];
    const float* b1 = (const float*)d_in[6];
    const float* f1 = (const float*)d_in[7];
    const float* m2 = (const float*)d_in[8];
    const float* b2 = (const float*)d_in[9];
    const float* f2 = (const float*)d_in[10];
    const float* m3 = (const float*)d_in[11];
    const float* b3 = (const float*)d_in[12];
    const float* f3 = (const float*)d_in[13];
    const float* m4 = (const float*)d_in[14];
    const float* b4 = (const float*)d_in[15];

    fx4* out = (fx4*)d_out;
    fx4* lik = out + TOTAL / 4;

    eb_fused<<<NBLK, 256, 0, stream>>>(x, nz, m0, b0, f0, m1, b1, f1,
                                       m2, b2, f2, m3, b3, f3, m4, b4,
                                       out, lik);
}